// Round 3
// baseline (954.773 us; speedup 1.0000x reference)
//
#include <hip/hip_runtime.h>
#include <cfloat>

#define NROWS 131072
#define EDIM 256
#define NE 1024

#define BM 128
#define BN 128
#define BK 32

// ---------- numpy pairwise sum-of-squares for one 256-elem contiguous row ----------
// numpy pairwise_sum: n=256 > PW_BLOCKSIZE(128) -> split 128+128.
// Each 128-block: r[j]=a[j] (j<8); for i=8..120 step 8: r[j]+=a[i+j];
// res = ((r0+r1)+(r2+r3)) + ((r4+r5)+(r6+r7)).  Total = block0 + block1.
// Elements are fl(x*x) (materialized z*z array), added with plain fp32 adds (NO fma).
__device__ __forceinline__ float np_sumsq256(const float* __restrict__ row) {
    float s[2];
#pragma unroll
    for (int h = 0; h < 2; ++h) {
        const float* a = row + h * 128;
        float r[8];
#pragma unroll
        for (int j = 0; j < 8; ++j) r[j] = __fmul_rn(a[j], a[j]);
        for (int i = 8; i < 128; i += 8) {
#pragma unroll
            for (int j = 0; j < 8; ++j)
                r[j] = __fadd_rn(r[j], __fmul_rn(a[i + j], a[i + j]));
        }
        s[h] = __fadd_rn(__fadd_rn(__fadd_rn(r[0], r[1]), __fadd_rn(r[2], r[3])),
                         __fadd_rn(__fadd_rn(r[4], r[5]), __fadd_rn(r[6], r[7])));
    }
    return __fadd_rn(s[0], s[1]);
}

__global__ __launch_bounds__(256)
void rownorm_kernel(const float* __restrict__ x, float* __restrict__ out, int nrows) {
    int row = blockIdx.x * blockDim.x + threadIdx.x;
    if (row < nrows) out[row] = np_sumsq256(x + (size_t)row * EDIM);
}

// ---------- main: m = sequential-FMA chain over k ascending (OpenBLAS sgemm order),
//            d = fl(fl(z2+e2) - fl(2*m)), per-row argmin, lowest-index ties ----------
__global__ __launch_bounds__(256, 2)
void vq_main_kernel(const float* __restrict__ z,
                    const float* __restrict__ e,
                    const float* __restrict__ z2g,
                    const float* __restrict__ e2g,
                    float* __restrict__ out_zq,
                    float* __restrict__ out_idx,
                    double* __restrict__ partials) {
    __shared__ float A[BK][BM];     // z tile, k-major (16 KiB)
    __shared__ float Bm[BK][BN];    // e tile, k-major (16 KiB)
    __shared__ float e2s[BN];
    __shared__ int   fIdx[BM];
    __shared__ double dred[256];

    const int tid  = threadIdx.x;
    const int m0   = blockIdx.x * BM;
    const int trow = tid >> 4;   // 0..15 -> rows trow*8..+8
    const int tcol = tid & 15;   // 0..15 -> cols tcol*8..+8

    float z2r[8];
#pragma unroll
    for (int i = 0; i < 8; ++i) z2r[i] = z2g[m0 + trow * 8 + i];

    float bestV[8];
    int   bestI[8];
#pragma unroll
    for (int i = 0; i < 8; ++i) { bestV[i] = FLT_MAX; bestI[i] = 0; }

    for (int n0 = 0; n0 < NE; n0 += BN) {
        float acc[8][8];
#pragma unroll
        for (int i = 0; i < 8; ++i)
#pragma unroll
            for (int j = 0; j < 8; ++j) acc[i][j] = 0.f;

        __syncthreads();                       // prev-chunk readers done
        if (tid < BN) e2s[tid] = e2g[n0 + tid];

        for (int k0 = 0; k0 < EDIM; k0 += BK) {
            __syncthreads();                   // prev k-step compute done
#pragma unroll
            for (int s = 0; s < 4; ++s) {
                int q   = tid + 256 * s;       // 0..1023
                int row = q >> 3;              // 0..127
                int kc  = (q & 7) << 2;        // 0,4,...,28
                float4 va = *reinterpret_cast<const float4*>(z + (size_t)(m0 + row) * EDIM + k0 + kc);
                A[kc + 0][row] = va.x; A[kc + 1][row] = va.y;
                A[kc + 2][row] = va.z; A[kc + 3][row] = va.w;
                float4 vb = *reinterpret_cast<const float4*>(e + (size_t)(n0 + row) * EDIM + k0 + kc);
                Bm[kc + 0][row] = vb.x; Bm[kc + 1][row] = vb.y;
                Bm[kc + 2][row] = vb.z; Bm[kc + 3][row] = vb.w;
            }
            __syncthreads();
            // strict sequential FMA chain per (i,j), k ascending
#pragma unroll
            for (int k = 0; k < BK; ++k) {
                float a[8], b[8];
                *reinterpret_cast<float4*>(&a[0]) = *reinterpret_cast<const float4*>(&A[k][trow * 8]);
                *reinterpret_cast<float4*>(&a[4]) = *reinterpret_cast<const float4*>(&A[k][trow * 8 + 4]);
                *reinterpret_cast<float4*>(&b[0]) = *reinterpret_cast<const float4*>(&Bm[k][tcol * 8]);
                *reinterpret_cast<float4*>(&b[4]) = *reinterpret_cast<const float4*>(&Bm[k][tcol * 8 + 4]);
#pragma unroll
                for (int i = 0; i < 8; ++i)
#pragma unroll
                    for (int j = 0; j < 8; ++j)
                        acc[i][j] = __fmaf_rn(a[i], b[j], acc[i][j]);
            }
        }
        // d = fl(fl(z2 + e2) - 2*m); per-thread argmin, ascending col order
#pragma unroll
        for (int i = 0; i < 8; ++i) {
#pragma unroll
            for (int j = 0; j < 8; ++j) {
                int   n = n0 + tcol * 8 + j;
                float d = __fsub_rn(__fadd_rn(z2r[i], e2s[tcol * 8 + j]),
                                    __fmul_rn(2.0f, acc[i][j]));
                if (d < bestV[i]) { bestV[i] = d; bestI[i] = n; }   // strict < keeps lowest idx
            }
        }
    }

    // ---- merge 16 col-group threads per row via LDS (reuse A as scratch) ----
    __syncthreads();
    float* red_v = &A[0][0];                          // [BM][16] floats
    int*   red_i = reinterpret_cast<int*>(&Bm[0][0]); // [BM][16] ints
#pragma unroll
    for (int i = 0; i < 8; ++i) {
        int row = trow * 8 + i;
        red_v[row * 16 + tcol] = bestV[i];
        red_i[row * 16 + tcol] = bestI[i];
    }
    __syncthreads();

    if (tid < BM) {
        const int r = tid;
        float b1 = FLT_MAX; int i1 = 0x7fffffff;
        for (int t = 0; t < 16; ++t) {
            float v  = red_v[r * 16 + t];
            int   id = red_i[r * 16 + t];
            if (v < b1 || (v == b1 && id < i1)) { b1 = v; i1 = id; }
        }
        fIdx[r] = i1;
        out_idx[m0 + r] = (float)i1;
    }
    __syncthreads();

    // ---- z_q_st write + loss partial ----
    double lsum = 0.0;
    for (int r = 0; r < BM; ++r) {
        int   fi = fIdx[r];
        float zv = z[(size_t)(m0 + r) * EDIM + tid];
        float ev = e[(size_t)fi * EDIM + tid];
        float dd = __fsub_rn(ev, zv);                                  // z_q - z (fp32)
        out_zq[(size_t)(m0 + r) * EDIM + tid] = __fadd_rn(zv, dd);     // z + sg(z_q - z)
        lsum += (double)dd * (double)dd;
    }
    dred[tid] = lsum;
    __syncthreads();
#pragma unroll
    for (int s = 128; s > 0; s >>= 1) {
        if (tid < s) dred[tid] += dred[tid + s];
        __syncthreads();
    }
    if (tid == 0) partials[blockIdx.x] = dred[0];
}

// ---------- loss finalize ----------
__global__ void vq_loss_kernel(const double* __restrict__ partials, float* __restrict__ out_loss) {
    __shared__ double s[256];
    const int tid = threadIdx.x;
    double v = 0.0;
    for (int i = tid; i < NROWS / BM; i += 256) v += partials[i];
    s[tid] = v;
    __syncthreads();
    for (int k = 128; k > 0; k >>= 1) {
        if (tid < k) s[tid] += s[tid + k];
        __syncthreads();
    }
    if (tid == 0) {
        double mean = s[0] / ((double)NROWS * (double)EDIM);
        out_loss[0] = (float)(1.25 * mean);   // (1 + BETA) * mean((z_q - z)^2)
    }
}

extern "C" void kernel_launch(void* const* d_in, const int* in_sizes, int n_in,
                              void* d_out, int out_size, void* d_ws, size_t ws_size,
                              hipStream_t stream) {
    (void)n_in; (void)out_size; (void)ws_size;
    const float* z = (const float*)d_in[0];
    const float* e = (const float*)d_in[1];
    if (in_sizes[0] == NE * EDIM) {           // defensive: swap if input order differs
        const float* t = z; z = e; e = t;
    }
    float* out      = (float*)d_out;
    float* out_zq   = out;
    float* out_loss = out + (size_t)NROWS * EDIM;
    float* out_idx  = out_loss + 1;

    float*  z2g      = (float*)d_ws;                          // 512 KiB
    float*  e2g      = (float*)((char*)d_ws + 524288);        // 4 KiB
    double* partials = (double*)((char*)d_ws + 532480);       // 8 KiB

    rownorm_kernel<<<(NROWS + 255) / 256, 256, 0, stream>>>(z, z2g, NROWS);
    rownorm_kernel<<<(NE + 255) / 256, 256, 0, stream>>>(e, e2g, NE);
    vq_main_kernel<<<NROWS / BM, 256, 0, stream>>>(z, e, z2g, e2g, out_zq, out_idx, partials);
    vq_loss_kernel<<<1, 256, 0, stream>>>(partials, out_loss);
}